// Round 26
// baseline (274.765 us; speedup 1.0000x reference)
//
#include <hip/hip_runtime.h>
#include <math.h>

#define HWSZ 4096   // 64*64
#define DIM  64
#define KCW  512
#define NROW 131072 // 32*4096
#define CMAX 8

typedef short bf16x8 __attribute__((ext_vector_type(8)));
typedef float f32x4  __attribute__((ext_vector_type(4)));

// ws float layout: [64..576) csq; [1024..17408) bf16 blob; [17408..21504) wave loss partials
#define WS_CSQ  64
#define WS_BLOB 1024
#define WS_PART 17408

static __device__ __forceinline__ unsigned short f2bf(float f) {
    union { float f; unsigned u; } v; v.f = f;
    unsigned u = v.u;
    return (unsigned short)((u + 0x7fffu + ((u >> 16) & 1u)) >> 16);  // RNE
}

// prep: exact fp32 csq, codebook -> bf16 fragment blob
// blob[((kt*2+f)*64 + l)*8 + j] = bf16(cw[kt*16 + (l&15)][f*32 + (l>>4)*8 + j])
__global__ void vq_prep_kernel(const float* __restrict__ cw, float* __restrict__ ws) {
    int tg = blockIdx.x * 256 + threadIdx.x;
    if (tg < KCW) {
        const float4* c4 = (const float4*)(cw + (size_t)tg * DIM);
        float s0 = 0.f, s1 = 0.f, s2 = 0.f, s3 = 0.f;
        #pragma unroll
        for (int i = 0; i < 16; ++i) {
            float4 c = c4[i];
            s0 = fmaf(c.x, c.x, s0); s1 = fmaf(c.y, c.y, s1);
            s2 = fmaf(c.z, c.z, s2); s3 = fmaf(c.w, c.w, s3);
        }
        ws[WS_CSQ + tg] = (s0 + s1) + (s2 + s3);
    }
    if (tg < 4096) {
        int l = tg & 63, f = (tg >> 6) & 1, kt = tg >> 7;
        int col = kt * 16 + (l & 15);
        unsigned short* blob = (unsigned short*)(ws + WS_BLOB);
        #pragma unroll
        for (int j = 0; j < 8; ++j) {
            int d = f * 32 + (l >> 4) * 8 + j;
            blob[((kt * 2 + f) * 64 + l) * 8 + j] = f2bf(cw[col * DIM + d]);
        }
    }
}

// SINGLE-SWEEP one-barrier kernel: 8 waves x 32 rows (512 thr, grid 512).
// Blob + csq in block LDS. R26: sweep 2 is GONE -- each lane tracks its two
// smallest scores (m1,m2 + packed kts) per row-slot during the single sweep.
// After the 16-lane min-reduce, thr = min + 2b + eps (proven margin):
//   m1 <= thr -> capture k1;  m2 <= thr -> FLAG the row (lane might hide a
// 3rd qualifying score) -> flagged rows take the exact full scan.
// Proof: argmin k* on lane L has s~(k*) <= thr; either s~(k*) in {m1,m2}
// (captured/flagged) or s~(k*) > m2 => m2 <= thr => flagged => scanned. Flag
// rate ~1-2% of rows. Removes 128 MFMA + 128 ds_read_b128 per wave.
// waves_per_eu(2,4): 256-reg budget (no 64-reg crush; spill configs are
// HBM-bound on 90MB of scratch -- R19/R25 post-mortem), max 16 waves/CU.
// canda int (dword-granular, R22 race fix).
__global__ __attribute__((amdgpu_flat_work_group_size(512, 512), amdgpu_waves_per_eu(2, 4)))
void vq_main_kernel(const float* __restrict__ in, const float* __restrict__ cw,
                    const float* __restrict__ ws_ro, float* __restrict__ part,
                    float* __restrict__ out) {
    __shared__ __align__(16) unsigned short blob_l[4096 * 8];  // 64 KB
    __shared__ float csq_l[KCW];                               // 2 KB
    __shared__ float xsqa[8][32];
    __shared__ int   sidxa[8][32];
    __shared__ int   cntsa[8][32];
    __shared__ int   flaga[8][32];
    __shared__ int   canda[8][32][CMAX];                       // 8 KB, dword-granular

    const int t  = threadIdx.x;
    const int w  = t >> 6, l = t & 63;
    const int hi = l >> 4, cl = l & 15;

    const int b    = blockIdx.x >> 4;        // 16 blocks per image (256 rows each)
    const int hwW  = (blockIdx.x & 15) * 256 + w * 32;
    const int rowW = blockIdx.x * 256 + w * 32;

    // ---- stage blob + csq into block LDS (one coalesced pass)
    {
        const float4* __restrict__ bg = (const float4*)(ws_ro + WS_BLOB);
        float4* bl4 = (float4*)blob_l;
        #pragma unroll
        for (int i = 0; i < 8; ++i) bl4[i * 512 + t] = bg[i * 512 + t];
        csq_l[t] = ws_ro[WS_CSQ + t];
    }
    if (l < 32) { cntsa[w][l] = 0; flaga[w][l] = 0; }

    const float* __restrict__ xg = in + (size_t)b * (DIM * HWSZ) + hwW;

    // ---- exact ||x||^2 from global (reference serial rounding), lanes 0..31
    if (l < 32) {
        float s = 0.f;
        for (int d = 0; d < DIM; ++d) { float xv = xg[(size_t)d * HWSZ + l]; s = fmaf(xv, xv, s); }
        xsqa[w][l] = s;
    }

    // ---- A fragments bf16(-x) from global (L2-hot after first touch)
    bf16x8 a00, a01, a10, a11;
    #pragma unroll
    for (int j = 0; j < 8; ++j) {
        a00[j] = (short)f2bf(-xg[(size_t)(hi * 8 + j) * HWSZ + cl]);
        a01[j] = (short)f2bf(-xg[(size_t)(32 + hi * 8 + j) * HWSZ + cl]);
        a10[j] = (short)f2bf(-xg[(size_t)(hi * 8 + j) * HWSZ + 16 + cl]);
        a11[j] = (short)f2bf(-xg[(size_t)(32 + hi * 8 + j) * HWSZ + 16 + cl]);
    }

    __syncthreads();                          // blob_l/csq_l ready (the ONLY barrier)

    const bf16x8* __restrict__ bls = (const bf16x8*)blob_l;

    // ---- single sweep: per-lane best-2 (m1<=m2) + packed kts, both row groups
    float m1_0[4], m2_0[4], m1_1[4], m2_1[4];
    int   kp0[4], kp1[4];                     // kt1 | (kt2<<8)
    #pragma unroll
    for (int rg = 0; rg < 4; ++rg) {
        m1_0[rg] = INFINITY; m2_0[rg] = INFINITY; kp0[rg] = 0;
        m1_1[rg] = INFINITY; m2_1[rg] = INFINITY; kp1[rg] = 0;
    }
    #pragma unroll 2
    for (int kt = 0; kt < 32; ++kt) {
        float ci = 0.5f * csq_l[kt * 16 + cl];
        bf16x8 b0 = bls[(kt * 2 + 0) * 64 + l];
        bf16x8 b1 = bls[(kt * 2 + 1) * 64 + l];
        f32x4 acc0 = {ci, ci, ci, ci};
        f32x4 acc1 = {ci, ci, ci, ci};
        acc0 = __builtin_amdgcn_mfma_f32_16x16x32_bf16(a00, b0, acc0, 0, 0, 0);
        acc0 = __builtin_amdgcn_mfma_f32_16x16x32_bf16(a01, b1, acc0, 0, 0, 0);
        acc1 = __builtin_amdgcn_mfma_f32_16x16x32_bf16(a10, b0, acc1, 0, 0, 0);
        acc1 = __builtin_amdgcn_mfma_f32_16x16x32_bf16(a11, b1, acc1, 0, 0, 0);
        #pragma unroll
        for (int rg = 0; rg < 4; ++rg) {
            float v0 = acc0[rg];
            if (v0 < m1_0[rg]) {
                m2_0[rg] = m1_0[rg];
                kp0[rg] = ((kp0[rg] & 0xff) << 8) | kt;
                m1_0[rg] = v0;
            } else if (v0 < m2_0[rg]) {
                m2_0[rg] = v0;
                kp0[rg] = (kp0[rg] & 0xff) | (kt << 8);
            }
            float v1 = acc1[rg];
            if (v1 < m1_1[rg]) {
                m2_1[rg] = m1_1[rg];
                kp1[rg] = ((kp1[rg] & 0xff) << 8) | kt;
                m1_1[rg] = v1;
            } else if (v1 < m2_1[rg]) {
                m2_1[rg] = v1;
                kp1[rg] = (kp1[rg] & 0xff) | (kt << 8);
            }
        }
    }

    // ---- final per-row min across the 16 col-lanes (copies; per-lane m1 kept)
    float gm0[4], gm1[4];
    #pragma unroll
    for (int rg = 0; rg < 4; ++rg) { gm0[rg] = m1_0[rg]; gm1[rg] = m1_1[rg]; }
    #pragma unroll
    for (int off = 1; off < 16; off <<= 1)
        #pragma unroll
        for (int rg = 0; rg < 4; ++rg) {
            gm0[rg] = fminf(gm0[rg], __shfl_xor(gm0[rg], off, 64));
            gm1[rg] = fminf(gm1[rg], __shfl_xor(gm1[rg], off, 64));
        }

    // ---- capture / flag: marg = 2*beta + eps = 0.0625*||x|| + 0.03125 (proven)
    #pragma unroll
    for (int rg = 0; rg < 4; ++rg) {
        {
            const int r = 4 * hi + rg;
            float thr = gm0[rg] + 0.0625f * sqrtf(xsqa[w][r]) + 0.03125f;
            if (m1_0[rg] <= thr) {
                int pos = atomicAdd(&cntsa[w][r], 1);
                if (pos < CMAX) canda[w][r][pos] = (kp0[rg] & 0xff) * 16 + cl;
            }
            if (m2_0[rg] <= thr) atomicOr(&flaga[w][r], 1);   // possible hidden 3rd
        }
        {
            const int r = 16 + 4 * hi + rg;
            float thr = gm1[rg] + 0.0625f * sqrtf(xsqa[w][r]) + 0.03125f;
            if (m1_1[rg] <= thr) {
                int pos = atomicAdd(&cntsa[w][r], 1);
                if (pos < CMAX) canda[w][r][pos] = (kp1[rg] & 0xff) * 16 + cl;
            }
            if (m2_1[rg] <= thr) atomicOr(&flaga[w][r], 1);
        }
    }

    // ---- exact fp32 refine: 2 lanes/row, x from global (skip flagged rows)
    {
        const int r = l >> 1, q = l & 1;
        const int n = cntsa[w][r];
        const float* __restrict__ xr = xg + r;
        if (flaga[w][r] == 0 && n <= CMAX) {  // n >= 1 (argmin's lane captured it)
            float bb = INFINITY; int bkk = 0x7fffffff;
            const float xsqe = xsqa[w][r];
            for (int s = q; s < n; s += 2) {
                int k = canda[w][r][s];
                const float4* __restrict__ c4 = (const float4*)(cw + (size_t)k * DIM);
                float d0 = 0.f, d1 = 0.f, d2 = 0.f, d3 = 0.f;
                #pragma unroll
                for (int i = 0; i < 16; ++i) {
                    float4 c = c4[i];
                    d0 = fmaf(xr[(size_t)(4 * i + 0) * HWSZ], c.x, d0);
                    d1 = fmaf(xr[(size_t)(4 * i + 1) * HWSZ], c.y, d1);
                    d2 = fmaf(xr[(size_t)(4 * i + 2) * HWSZ], c.z, d2);
                    d3 = fmaf(xr[(size_t)(4 * i + 3) * HWSZ], c.w, d3);
                }
                float dot  = (d0 + d1) + (d2 + d3);
                float dist = (xsqe + csq_l[k]) - 2.f * dot;  // reference rounding order
                if (dist < bb || (dist == bb && k < bkk)) { bb = dist; bkk = k; }
            }
            {
                float ob = __shfl_xor(bb, 1, 64);
                int   ok = __shfl_xor(bkk, 1, 64);
                if (ob < bb || (ob == bb && ok < bkk)) { bb = ob; bkk = ok; }
            }
            if (q == 0) {
                sidxa[w][r] = bkk;
                out[(size_t)NROW * DIM + rowW + r] = (float)bkk;
            }
        }
    }

    // ---- flagged / overflow rows: wave-local exact full scan (rare, ~1-2%)
    for (int r = 0; r < 32; ++r) {
        if (flaga[w][r] == 0 && cntsa[w][r] <= CMAX) continue;   // wave-uniform
        const float xsqe = xsqa[w][r];
        const float* __restrict__ xr = xg + r;
        float bb = INFINITY; int bkk = 0x7fffffff;
        for (int kk = 0; kk < 8; ++kk) {
            int k = kk * 64 + l;
            const float4* __restrict__ c4 = (const float4*)(cw + (size_t)k * DIM);
            float d0 = 0.f, d1 = 0.f, d2 = 0.f, d3 = 0.f;
            #pragma unroll
            for (int i = 0; i < 16; ++i) {
                float4 c = c4[i];
                d0 = fmaf(xr[(size_t)(4 * i + 0) * HWSZ], c.x, d0);
                d1 = fmaf(xr[(size_t)(4 * i + 1) * HWSZ], c.y, d1);
                d2 = fmaf(xr[(size_t)(4 * i + 2) * HWSZ], c.z, d2);
                d3 = fmaf(xr[(size_t)(4 * i + 3) * HWSZ], c.w, d3);
            }
            float dot  = (d0 + d1) + (d2 + d3);
            float dist = (xsqe + csq_l[k]) - 2.f * dot;
            if (dist < bb || (dist == bb && k < bkk)) { bb = dist; bkk = k; }
        }
        #pragma unroll
        for (int off = 32; off; off >>= 1) {
            float ob = __shfl_down(bb, off, 64);
            int   ok = __shfl_down(bkk, off, 64);
            if (ob < bb || (ob == bb && ok < bkk)) { bb = ob; bkk = ok; }
        }
        if (l == 0) {
            sidxa[w][r] = bkk;
            out[(size_t)NROW * DIM + rowW + r] = (float)bkk;
        }
    }

    // ---- epilogue: 2 lanes/row (32 dims each); full-128B-line stores
    {
        const int r = l >> 1, q2 = l & 1;
        const int kwin = sidxa[w][r];
        const float4* __restrict__ qp = (const float4*)(cw + (size_t)kwin * DIM + q2 * 32);
        const float* __restrict__ xe = xg + r;
        float* __restrict__ obase = out + (size_t)b * (DIM * HWSZ) + hwW + r;
        float lsum = 0.f;
        #pragma unroll
        for (int dd = 0; dd < 8; ++dd) {
            float4 q4 = qp[dd];
            float qv[4] = {q4.x, q4.y, q4.z, q4.w};
            #pragma unroll
            for (int c = 0; c < 4; ++c) {
                int d = q2 * 32 + dd * 4 + c;
                float xv = xe[(size_t)d * HWSZ];
                obase[(size_t)d * HWSZ] = qv[c];
                float diff = qv[c] - xv;
                lsum = fmaf(diff, diff, lsum);
            }
        }
        #pragma unroll
        for (int off = 32; off; off >>= 1) lsum += __shfl_down(lsum, off, 64);
        if (l == 0) part[blockIdx.x * 8 + w] = lsum;
    }
}

__global__ void vq_finalize_kernel(const float* __restrict__ part, float* __restrict__ out) {
    __shared__ float wsum[4];
    const int t = threadIdx.x;
    float s = 0.f;
    #pragma unroll
    for (int i = 0; i < 16; ++i) s += part[t * 16 + i];   // 4096 partials, fixed order
    #pragma unroll
    for (int off = 32; off; off >>= 1) s += __shfl_down(s, off, 64);
    if ((t & 63) == 0) wsum[t >> 6] = s;
    __syncthreads();
    if (t == 0)
        out[(size_t)NROW * DIM + NROW] =
            1.25f * ((wsum[0] + wsum[1]) + (wsum[2] + wsum[3])) / (float)((size_t)NROW * DIM);
}

extern "C" void kernel_launch(void* const* d_in, const int* in_sizes, int n_in,
                              void* d_out, int out_size, void* d_ws, size_t ws_size,
                              hipStream_t stream) {
    const float* in = (const float*)d_in[0];
    const float* cw = (const float*)d_in[1];
    float* out = (float*)d_out;
    float* ws  = (float*)d_ws;

    hipLaunchKernelGGL(vq_prep_kernel, dim3(16), dim3(256), 0, stream, cw, ws);
    hipLaunchKernelGGL(vq_main_kernel, dim3(NROW / 256), dim3(512), 0, stream,
                       in, cw, ws, ws + WS_PART, out);
    hipLaunchKernelGGL(vq_finalize_kernel, dim3(1), dim3(256), 0, stream, ws + WS_PART, out);
}

// Round 27
// 114.634 us; speedup vs baseline: 2.3969x; 2.3969x over previous
//
#include <hip/hip_runtime.h>
#include <math.h>

#define HWSZ 4096   // 64*64
#define DIM  64
#define KCW  512
#define NROW 131072 // 32*4096
#define CMAX 8

typedef short bf16x8 __attribute__((ext_vector_type(8)));
typedef float f32x4  __attribute__((ext_vector_type(4)));

// ws float layout: [64..576) csq; [1024..17408) bf16 blob; [17408..19456) wave loss partials
#define WS_CSQ  64
#define WS_BLOB 1024
#define WS_PART 17408

static __device__ __forceinline__ unsigned short f2bf(float f) {
    union { float f; unsigned u; } v; v.f = f;
    unsigned u = v.u;
    return (unsigned short)((u + 0x7fffu + ((u >> 16) & 1u)) >> 16);  // RNE
}

// prep: exact fp32 csq, codebook -> bf16 fragment blob
// blob[((kt*2+f)*64 + l)*8 + j] = bf16(cw[kt*16 + (l&15)][f*32 + (l>>4)*8 + j])
__global__ void vq_prep_kernel(const float* __restrict__ cw, float* __restrict__ ws) {
    int tg = blockIdx.x * 256 + threadIdx.x;
    if (tg < KCW) {
        const float4* c4 = (const float4*)(cw + (size_t)tg * DIM);
        float s0 = 0.f, s1 = 0.f, s2 = 0.f, s3 = 0.f;
        #pragma unroll
        for (int i = 0; i < 16; ++i) {
            float4 c = c4[i];
            s0 = fmaf(c.x, c.x, s0); s1 = fmaf(c.y, c.y, s1);
            s2 = fmaf(c.z, c.z, s2); s3 = fmaf(c.w, c.w, s3);
        }
        ws[WS_CSQ + tg] = (s0 + s1) + (s2 + s3);
    }
    if (tg < 4096) {
        int l = tg & 63, f = (tg >> 6) & 1, kt = tg >> 7;
        int col = kt * 16 + (l & 15);
        unsigned short* blob = (unsigned short*)(ws + WS_BLOB);
        #pragma unroll
        for (int j = 0; j < 8; ++j) {
            int d = f * 32 + (l >> 4) * 8 + j;
            blob[((kt * 2 + f) * 64 + l) * 8 + j] = f2bf(cw[col * DIM + d]);
        }
    }
}

// ZERO-BARRIER kernel, 64 rows/wave (R18 structure), x ENTIRELY from global.
// R18 was LDS-capped at 8 waves/CU by its 81KB x-tile; x accesses are 128-256B
// coalesced + L2-hot (proven R19-R25), so the tile bought nothing. LDS drops
// to ~11KB -> occupancy is VGPR-limited: waves_per_eu(2,4) gives the 256-reg
// budget (no 64-reg crush -> no spill; R19/R25 showed spill configs are
// HBM-bound on their own scratch) and allows 4 waves/EU = 16 waves/CU at
// <=128 regs -- double R18. Per kt one B-frag pair (global, L2/L3-hot) feeds
// 8 MFMA (4 row-groups): ILP covers the ~200cy L2 latency. Two sweeps
// (R26's best-2 tracker was a serial-chain disaster -- recompute is cheaper).
// int canda (R22 dword-granularity race fix), CMAX=8 + exact-scan fallback.
__global__ __attribute__((amdgpu_flat_work_group_size(256, 256), amdgpu_waves_per_eu(2, 4)))
void vq_main_kernel(const float* __restrict__ in, const float* __restrict__ cw,
                    const float* __restrict__ ws_ro, float* __restrict__ part,
                    float* __restrict__ out) {
    __shared__ float xsqa[4][64];
    __shared__ int   sidxa[4][64];
    __shared__ int   cntsa[4][64];
    __shared__ int   canda[4][64][CMAX];     // 8 KB, dword-granular

    const int t  = threadIdx.x;
    const int w  = t >> 6, l = t & 63;
    const int hi = l >> 4, cl = l & 15;

    const int b    = blockIdx.x >> 4;        // 16 blocks per image (256 rows each)
    const int hwW  = (blockIdx.x & 15) * 256 + w * 64;
    const int rowW = blockIdx.x * 256 + w * 64;

    cntsa[w][l] = 0;

    const float* __restrict__ xg = in + (size_t)b * (DIM * HWSZ) + hwW;

    // ---- exact ||x||^2 from global (reference serial rounding), lane = row
    {
        float s = 0.f;
        #pragma unroll
        for (int d = 0; d < DIM; ++d) { float xv = xg[(size_t)d * HWSZ + l]; s = fmaf(xv, xv, s); }
        xsqa[w][l] = s;
    }

    // ---- A fragments bf16(-x), 4 row-groups x 2 K-halves, from global (L2-hot)
    bf16x8 af[4][2];
    #pragma unroll
    for (int rgp = 0; rgp < 4; ++rgp)
        #pragma unroll
        for (int f = 0; f < 2; ++f)
            #pragma unroll
            for (int j = 0; j < 8; ++j)
                af[rgp][f][j] = (short)f2bf(-xg[(size_t)(f * 32 + hi * 8 + j) * HWSZ + rgp * 16 + cl]);

    const bf16x8* __restrict__ bp   = (const bf16x8*)(ws_ro + WS_BLOB);
    const float*  __restrict__ csqg = ws_ro + WS_CSQ;

    // ---- sweep 1: per-lane running min over all 32 kt, 4 row-groups
    float mn[4][4];
    #pragma unroll
    for (int rgp = 0; rgp < 4; ++rgp)
        #pragma unroll
        for (int rg = 0; rg < 4; ++rg) mn[rgp][rg] = INFINITY;
    #pragma unroll 2
    for (int kt = 0; kt < 32; ++kt) {
        float ci = 0.5f * csqg[kt * 16 + cl];
        bf16x8 b0 = bp[(kt * 2 + 0) * 64 + l];
        bf16x8 b1 = bp[(kt * 2 + 1) * 64 + l];
        #pragma unroll
        for (int rgp = 0; rgp < 4; ++rgp) {
            f32x4 a = {ci, ci, ci, ci};
            a = __builtin_amdgcn_mfma_f32_16x16x32_bf16(af[rgp][0], b0, a, 0, 0, 0);
            a = __builtin_amdgcn_mfma_f32_16x16x32_bf16(af[rgp][1], b1, a, 0, 0, 0);
            #pragma unroll
            for (int rg = 0; rg < 4; ++rg) mn[rgp][rg] = fminf(mn[rgp][rg], a[rg]);
        }
    }
    #pragma unroll
    for (int off = 1; off < 16; off <<= 1)   // row-min across 16 col-lanes: FINAL
        #pragma unroll
        for (int rgp = 0; rgp < 4; ++rgp)
            #pragma unroll
            for (int rg = 0; rg < 4; ++rg)
                mn[rgp][rg] = fminf(mn[rgp][rg], __shfl_xor(mn[rgp][rg], off, 64));

    // thresholds: marg = 2*beta + eps = 0.0625*||x|| + 0.03125 (proven chain)
    float thr[4][4];
    #pragma unroll
    for (int rgp = 0; rgp < 4; ++rgp)
        #pragma unroll
        for (int rg = 0; rg < 4; ++rg)
            thr[rgp][rg] = mn[rgp][rg]
                         + 0.0625f * sqrtf(xsqa[w][rgp * 16 + 4 * hi + rg]) + 0.03125f;

    // ---- sweep 2: recompute, capture vs FINAL threshold (tight set, ~1-3/row)
    #pragma unroll 2
    for (int kt = 0; kt < 32; ++kt) {
        float ci = 0.5f * csqg[kt * 16 + cl];
        bf16x8 b0 = bp[(kt * 2 + 0) * 64 + l];
        bf16x8 b1 = bp[(kt * 2 + 1) * 64 + l];
        #pragma unroll
        for (int rgp = 0; rgp < 4; ++rgp) {
            f32x4 a = {ci, ci, ci, ci};
            a = __builtin_amdgcn_mfma_f32_16x16x32_bf16(af[rgp][0], b0, a, 0, 0, 0);
            a = __builtin_amdgcn_mfma_f32_16x16x32_bf16(af[rgp][1], b1, a, 0, 0, 0);
            #pragma unroll
            for (int rg = 0; rg < 4; ++rg) {
                if (a[rg] <= thr[rgp][rg]) {
                    int r = rgp * 16 + 4 * hi + rg;      // wave-private row
                    int pos = atomicAdd(&cntsa[w][r], 1);
                    if (pos < CMAX) canda[w][r][pos] = kt * 16 + cl;
                }
            }
        }
    }

    // ---- exact fp32 refine: ONE lane per row, x from global, lex tie-break
    {
        const int r = l;
        const int n = cntsa[w][r];
        const float* __restrict__ xr = xg + r;
        if (n <= CMAX) {                         // n >= 1 (argmin always captured)
            float bb = INFINITY; int bkk = 0x7fffffff;
            const float xsqe = xsqa[w][r];
            for (int s = 0; s < n; ++s) {
                int k = canda[w][r][s];
                const float4* __restrict__ c4 = (const float4*)(cw + (size_t)k * DIM);
                float d0 = 0.f, d1 = 0.f, d2 = 0.f, d3 = 0.f;
                #pragma unroll
                for (int i = 0; i < 16; ++i) {
                    float4 c = c4[i];
                    d0 = fmaf(xr[(size_t)(4 * i + 0) * HWSZ], c.x, d0);
                    d1 = fmaf(xr[(size_t)(4 * i + 1) * HWSZ], c.y, d1);
                    d2 = fmaf(xr[(size_t)(4 * i + 2) * HWSZ], c.z, d2);
                    d3 = fmaf(xr[(size_t)(4 * i + 3) * HWSZ], c.w, d3);
                }
                float dot  = (d0 + d1) + (d2 + d3);
                float dist = (xsqe + csqg[k]) - 2.f * dot;   // reference rounding order
                if (dist < bb || (dist == bb && k < bkk)) { bb = dist; bkk = k; }
            }
            sidxa[w][r] = bkk;
            out[(size_t)NROW * DIM + rowW + r] = (float)bkk;
        }
    }

    // ---- overflow rows (cnt > CMAX): wave-local exact full scan, 8 cols/lane
    for (int r = 0; r < 64; ++r) {
        if (cntsa[w][r] <= CMAX) continue;       // wave-uniform count
        const float xsqe = xsqa[w][r];
        const float* __restrict__ xr = xg + r;
        float bb = INFINITY; int bkk = 0x7fffffff;
        for (int kk = 0; kk < 8; ++kk) {
            int k = kk * 64 + l;
            const float4* __restrict__ c4 = (const float4*)(cw + (size_t)k * DIM);
            float d0 = 0.f, d1 = 0.f, d2 = 0.f, d3 = 0.f;
            #pragma unroll
            for (int i = 0; i < 16; ++i) {
                float4 c = c4[i];
                d0 = fmaf(xr[(size_t)(4 * i + 0) * HWSZ], c.x, d0);
                d1 = fmaf(xr[(size_t)(4 * i + 1) * HWSZ], c.y, d1);
                d2 = fmaf(xr[(size_t)(4 * i + 2) * HWSZ], c.z, d2);
                d3 = fmaf(xr[(size_t)(4 * i + 3) * HWSZ], c.w, d3);
            }
            float dot  = (d0 + d1) + (d2 + d3);
            float dist = (xsqe + csqg[k]) - 2.f * dot;
            if (dist < bb || (dist == bb && k < bkk)) { bb = dist; bkk = k; }
        }
        #pragma unroll
        for (int off = 32; off; off >>= 1) {
            float ob = __shfl_down(bb, off, 64);
            int   ok = __shfl_down(bkk, off, 64);
            if (ob < bb || (ob == bb && ok < bkk)) { bb = ob; bkk = ok; }
        }
        if (l == 0) {
            sidxa[w][r] = bkk;
            out[(size_t)NROW * DIM + rowW + r] = (float)bkk;
        }
    }

    // ---- epilogue: ONE lane per row; stores are full 256B lines per d
    {
        const int r = l;
        const int kwin = sidxa[w][r];
        const float4* __restrict__ qp = (const float4*)(cw + (size_t)kwin * DIM);
        const float* __restrict__ xe = xg + r;
        float* __restrict__ obase = out + (size_t)b * (DIM * HWSZ) + hwW + r;
        float lsum = 0.f;
        #pragma unroll
        for (int dd = 0; dd < 16; ++dd) {
            float4 q4 = qp[dd];
            float qv[4] = {q4.x, q4.y, q4.z, q4.w};
            #pragma unroll
            for (int c = 0; c < 4; ++c) {
                int d = dd * 4 + c;
                float xv = xe[(size_t)d * HWSZ];
                obase[(size_t)d * HWSZ] = qv[c];
                float diff = qv[c] - xv;
                lsum = fmaf(diff, diff, lsum);
            }
        }
        #pragma unroll
        for (int off = 32; off; off >>= 1) lsum += __shfl_down(lsum, off, 64);
        if (l == 0) part[blockIdx.x * 4 + w] = lsum;
    }
}

__global__ void vq_finalize_kernel(const float* __restrict__ part, float* __restrict__ out) {
    __shared__ float wsum[4];
    const int t = threadIdx.x;
    float s = 0.f;
    #pragma unroll
    for (int i = 0; i < 8; ++i) s += part[t * 8 + i];     // 2048 partials, fixed order
    #pragma unroll
    for (int off = 32; off; off >>= 1) s += __shfl_down(s, off, 64);
    if ((t & 63) == 0) wsum[t >> 6] = s;
    __syncthreads();
    if (t == 0)
        out[(size_t)NROW * DIM + NROW] =
            1.25f * ((wsum[0] + wsum[1]) + (wsum[2] + wsum[3])) / (float)((size_t)NROW * DIM);
}

extern "C" void kernel_launch(void* const* d_in, const int* in_sizes, int n_in,
                              void* d_out, int out_size, void* d_ws, size_t ws_size,
                              hipStream_t stream) {
    const float* in = (const float*)d_in[0];
    const float* cw = (const float*)d_in[1];
    float* out = (float*)d_out;
    float* ws  = (float*)d_ws;

    hipLaunchKernelGGL(vq_prep_kernel, dim3(16), dim3(256), 0, stream, cw, ws);
    hipLaunchKernelGGL(vq_main_kernel, dim3(NROW / 256), dim3(256), 0, stream,
                       in, cw, ws, ws + WS_PART, out);
    hipLaunchKernelGGL(vq_finalize_kernel, dim3(1), dim3(256), 0, stream, ws + WS_PART, out);
}